// Round 6
// baseline (46.949 us; speedup 1.0000x reference)
//
#include <hip/hip_runtime.h>
#include <math.h>

// Problem dims (fixed by setup_inputs)
#define NROWS 8192   // B*S
#define DIN   1024
#define NT    12
#define NDEP  3
#define NDEC  36     // NT*NDEP
#define NCOL  48     // 36 decision + 12 gate logits
#define NC    96     // NT*NLEAF
#define NH    3
#define DOUT  512
#define LRP   52     // padded Lred row (f32)

typedef short bf16x8 __attribute__((ext_vector_type(8)));   // 8 bf16 = 4 VGPRs (MFMA A/B frag)
typedef float f32x4  __attribute__((ext_vector_type(4)));   // MFMA C/D frag

__device__ inline unsigned short f2bf(float f) {            // round-to-nearest-even
    unsigned u = __float_as_uint(f);
    u = u + 0x7fff + ((u >> 16) & 1);
    return (unsigned short)(u >> 16);
}
__device__ inline float bf2f(unsigned short h) {
    return __uint_as_float(((unsigned)h) << 16);
}
// packed RTNE f32x2 -> bf16x2 (low16 = a, high16 = b)
__device__ inline unsigned cvt_pk(float a, float b) {
    unsigned r;
    asm("v_cvt_pk_bf16_f32 %0, %1, %2" : "=v"(r) : "v"(a), "v"(b));
    return r;
}
// split 8 consecutive f32 into bf16 hi + bf16 lo fragments (exact residual)
__device__ inline void split8(const float4 a, const float4 b, bf16x8& hi, bf16x8& lo) {
    union U { unsigned u[4]; bf16x8 v; };
    U H, L;
    H.u[0] = cvt_pk(a.x, a.y); H.u[1] = cvt_pk(a.z, a.w);
    H.u[2] = cvt_pk(b.x, b.y); H.u[3] = cvt_pk(b.z, b.w);
    const float r0 = a.x - __uint_as_float(H.u[0] << 16);
    const float r1 = a.y - __uint_as_float(H.u[0] & 0xffff0000u);
    const float r2 = a.z - __uint_as_float(H.u[1] << 16);
    const float r3 = a.w - __uint_as_float(H.u[1] & 0xffff0000u);
    const float r4 = b.x - __uint_as_float(H.u[2] << 16);
    const float r5 = b.y - __uint_as_float(H.u[2] & 0xffff0000u);
    const float r6 = b.z - __uint_as_float(H.u[3] << 16);
    const float r7 = b.w - __uint_as_float(H.u[3] & 0xffff0000u);
    L.u[0] = cvt_pk(r0, r1); L.u[1] = cvt_pk(r2, r3);
    L.u[2] = cvt_pk(r4, r5); L.u[3] = cvt_pk(r6, r7);
    hi = H.v; lo = L.v;
}

// ---------------------------------------------------------------------------
// k_prep (merged): blocks [0,192): W[48][1024] -> bf16 hi/lo split ([n][k]);
// blocks [192,264): leafT[h][d][k] bf16; block 264: param tables.
// ---------------------------------------------------------------------------
__global__ __launch_bounds__(256) void k_prep(const float* __restrict__ dw,
                                              const float* __restrict__ gw,
                                              const float* __restrict__ db,
                                              const float* __restrict__ ntl,
                                              const float* __restrict__ leaf,
                                              unsigned short* __restrict__ w_hi,
                                              unsigned short* __restrict__ w_lo,
                                              unsigned short* __restrict__ leafT,
                                              float* __restrict__ it_zb) {
    const int b = blockIdx.x;
    if (b < 192) {
        const int i = b * 256 + threadIdx.x;        // n*1024 + k
        const int n = i >> 10;
        const float v = (n < NDEC) ? dw[i] : gw[i - NDEC * DIN];
        const unsigned short h = f2bf(v);
        w_hi[i] = h;
        w_lo[i] = f2bf(v - bf2f(h));
    } else if (b < 264) {
        const int i  = (b - 192) * 256 + threadIdx.x;   // 0 .. 18431
        const int hq = i % (NH * DOUT);                 // h*512 + d
        const int kq = i / (NH * DOUT);                 // 0..11
        const int h  = hq >> 9, d = hq & 511;
        bf16x8 v;
#pragma unroll
        for (int e = 0; e < 8; ++e)
            v[e] = (short)f2bf(leaf[(size_t)(h * NC + kq * 8 + e) * DOUT + d]);
        *(bf16x8*)(leafT + (size_t)hq * NC + kq * 8) = v;
    } else {
        const int i = threadIdx.x;
        if (i < NDEC) {
            const float v  = ntl[i] + 0.5413f;
            const float sp = (v > 20.0f) ? v : logf(1.0f + expf(v));
            const float it = 1.0f / sp;
            it_zb[i]        = it;            // inv_temp
            it_zb[NDEC + i] = db[i] * it;    // pre-scaled bias
        }
    }
}

// ---------------------------------------------------------------------------
// k_A: GEMM1 + epilogue.  Block = 16 rows, 8 waves (512 thr), wave w covers
// K-chunk [w*128,(w+1)*128) with split-bf16 MFMA (A=w, B=x -> f32x4 LDS
// write).  LDS reduce over 8 partials, sigmoid/leaf/softmax epilogue, write
// C bf16[16][96] to global (192B/row contiguous).
// ---------------------------------------------------------------------------
__global__ __launch_bounds__(512) void k_A(const float* __restrict__ x,
                                           const unsigned short* __restrict__ w_hi,
                                           const unsigned short* __restrict__ w_lo,
                                           const float* __restrict__ it_zb,
                                           const float* __restrict__ gb,
                                           unsigned short* __restrict__ Cg) {
    __shared__ __align__(16) float Lred[8][16][LRP];     // [wave][row][wcol]

    const int tid  = threadIdx.x;
    const int wv   = tid >> 6, lane = tid & 63;
    const int m    = lane & 15;                         // A: w-col / B: x-row
    const int kq   = lane >> 4;                         // k quarter (0..3)
    const int row0 = blockIdx.x * 16;

    f32x4 acc[3];
#pragma unroll
    for (int nf = 0; nf < 3; ++nf)
#pragma unroll
        for (int r = 0; r < 4; ++r) acc[nf][r] = 0.0f;

    const float*          xp  = x    + (size_t)(row0 + m) * DIN + wv * 128 + kq * 8;
    const unsigned short* whp = w_hi + (size_t)m * DIN + wv * 128 + kq * 8;
    const unsigned short* wlp = w_lo + (size_t)m * DIN + wv * 128 + kq * 8;

#pragma unroll 2
    for (int ks = 0; ks < 4; ++ks) {
        const float4 xa = *(const float4*)(xp + ks * 32);
        const float4 xb = *(const float4*)(xp + ks * 32 + 4);
        bf16x8 xhi, xlo;
        split8(xa, xb, xhi, xlo);
#pragma unroll
        for (int nf = 0; nf < 3; ++nf) {
            const bf16x8 whi = *(const bf16x8*)(whp + (size_t)nf * 16 * DIN + ks * 32);
            const bf16x8 wlo = *(const bf16x8*)(wlp + (size_t)nf * 16 * DIN + ks * 32);
            acc[nf] = __builtin_amdgcn_mfma_f32_16x16x32_bf16(whi, xhi, acc[nf], 0, 0, 0);
            acc[nf] = __builtin_amdgcn_mfma_f32_16x16x32_bf16(whi, xlo, acc[nf], 0, 0, 0);
            acc[nf] = __builtin_amdgcn_mfma_f32_16x16x32_bf16(wlo, xhi, acc[nf], 0, 0, 0);
        }
    }
    // D: col(lane&15) = x-row, rows = 4 consecutive w-cols -> float4 LDS write
#pragma unroll
    for (int nf = 0; nf < 3; ++nf)
        *(f32x4*)&Lred[wv][m][nf * 16 + kq * 4] = acc[nf];
    __syncthreads();

    if (tid < 256) {
        const int erow = tid >> 4;      // 0..15  (row within block)
        const int slot = tid & 15;      // 0..11 = tree, 12..15 idle
        float lg0 = 0.f, lg1 = 0.f, lg2 = 0.f, g = -1e30f;
        if (slot < NT) {
            float lgg = 0.f;
#pragma unroll
            for (int w = 0; w < 8; ++w) {
                lg0 += Lred[w][erow][slot * 3 + 0];
                lg1 += Lred[w][erow][slot * 3 + 1];
                lg2 += Lred[w][erow][slot * 3 + 2];
                lgg += Lred[w][erow][NDEC + slot];
            }
            g = lgg + gb[slot];
        }
        // softmax over the 16-lane row-group (slots >= 12 contribute 0)
        float mx = g;
#pragma unroll
        for (int off = 1; off < 16; off <<= 1) mx = fmaxf(mx, __shfl_xor(mx, off, 16));
        const float e = (slot < NT) ? expf(g - mx) : 0.f;
        float s = e;
#pragma unroll
        for (int off = 1; off < 16; off <<= 1) s += __shfl_xor(s, off, 16);
        if (slot < NT) {
            const float wt = e * __builtin_amdgcn_rcpf(s);
            const float z0 = lg0 * it_zb[slot * 3 + 0] + it_zb[NDEC + slot * 3 + 0];
            const float z1 = lg1 * it_zb[slot * 3 + 1] + it_zb[NDEC + slot * 3 + 1];
            const float z2 = lg2 * it_zb[slot * 3 + 2] + it_zb[NDEC + slot * 3 + 2];
            const float d0 = __builtin_amdgcn_rcpf(1.0f + expf(-z0));
            const float d1 = __builtin_amdgcn_rcpf(1.0f + expf(-z1));
            const float d2 = __builtin_amdgcn_rcpf(1.0f + expf(-z2));
            float c[8];
#pragma unroll
            for (int l = 0; l < 8; ++l) {
                const float p0 = (l & 4) ? (1.0f - d0) : d0;
                const float p1 = (l & 2) ? (1.0f - d1) : d1;
                const float p2 = (l & 1) ? (1.0f - d2) : d2;
                c[l] = wt * p0 * p1 * p2;
            }
            union { unsigned u[4]; bf16x8 v; } P;
            P.u[0] = cvt_pk(c[0], c[1]); P.u[1] = cvt_pk(c[2], c[3]);
            P.u[2] = cvt_pk(c[4], c[5]); P.u[3] = cvt_pk(c[6], c[7]);
            *(bf16x8*)(Cg + (size_t)(row0 + erow) * NC + slot * 8) = P.v;
        }
    }
}

// ---------------------------------------------------------------------------
// k_B: GEMM2 only.  out[h][row][d] = sum_k C[row][k] * leafT[h][d][k]
// Block = 256 thr / 4 waves, NO LDS, NO barriers.  Wave = 16 rows x 64
// consecutive d (4 frags); block = 16 rows x 256 d.  Grid (512, 6) = 3072
// blocks -> 12 blocks/CU.  A=leafT, B=C -> f32x4 coalesced stores.
// ---------------------------------------------------------------------------
__global__ __launch_bounds__(256) void k_B(const unsigned short* __restrict__ Cg,
                                           const unsigned short* __restrict__ leafT,
                                           float* __restrict__ out) {
    const int tid   = threadIdx.x;
    const int wv    = tid >> 6, lane = tid & 63;
    const int m     = lane & 15;
    const int kq    = lane >> 4;
    const int row0  = blockIdx.x * 16;
    const int fbase = blockIdx.y * 16 + wv * 4;   // 4 consecutive d-frags, one h

    // B-frags: C rows (L2-resident, 1.5 MB total)
    bf16x8 cfr[3];
    const unsigned short* cp = Cg + (size_t)(row0 + m) * NC + kq * 8;
#pragma unroll
    for (int ks = 0; ks < 3; ++ks)
        cfr[ks] = *(const bf16x8*)(cp + ks * 32);

#pragma unroll
    for (int i = 0; i < 4; ++i) {
        const int f  = fbase + i;             // 0..95
        const int h  = f >> 5;
        const int d0 = (f & 31) * 16;
        const unsigned short* bp = leafT + ((size_t)h * DOUT + d0 + m) * NC + kq * 8;
        f32x4 a;
#pragma unroll
        for (int r = 0; r < 4; ++r) a[r] = 0.0f;
#pragma unroll
        for (int ks = 0; ks < 3; ++ks) {
            const bf16x8 lfr = *(const bf16x8*)(bp + ks * 32);
            a = __builtin_amdgcn_mfma_f32_16x16x32_bf16(lfr, cfr[ks], a, 0, 0, 0);
        }
        // D: col(lane&15) = out-row, regs = 4 consecutive d -> float4 store
        *(f32x4*)(out + ((size_t)h * NROWS + row0 + m) * DOUT + d0 + kq * 4) = a;
    }
}

extern "C" void kernel_launch(void* const* d_in, const int* in_sizes, int n_in,
                              void* d_out, int out_size, void* d_ws, size_t ws_size,
                              hipStream_t stream) {
    const float* x    = (const float*)d_in[0];
    const float* dw   = (const float*)d_in[1];
    const float* db   = (const float*)d_in[2];
    const float* ntl  = (const float*)d_in[3];
    const float* gw   = (const float*)d_in[4];
    const float* gb   = (const float*)d_in[5];
    const float* leaf = (const float*)d_in[6];
    float* out = (float*)d_out;

    // workspace carve (byte offsets, all 16B-aligned)
    char* ws = (char*)d_ws;
    unsigned short* w_hi  = (unsigned short*)(ws);            // 48*1024*2 =  98304 B
    unsigned short* w_lo  = (unsigned short*)(ws + 98304);    //              98304 B
    unsigned short* leafT = (unsigned short*)(ws + 196608);   // 3*512*96*2 = 294912 B
    float*          it_zb = (float*)(ws + 491520);            // 72*4       =    288 B
    unsigned short* Cg    = (unsigned short*)(ws + 524288);   // 8192*96*2  = 1572864 B

    k_prep<<<265, 256, 0, stream>>>(dw, gw, db, ntl, leaf, w_hi, w_lo, leafT, it_zb);
    k_A<<<NROWS / 16, 512, 0, stream>>>(x, w_hi, w_lo, it_zb, gb, Cg);
    k_B<<<dim3(NROWS / 16, 6), 256, 0, stream>>>(Cg, leafT, out);
}

// Round 7
// 43.524 us; speedup vs baseline: 1.0787x; 1.0787x over previous
//
#include <hip/hip_runtime.h>
#include <math.h>

// Problem dims (fixed by setup_inputs)
#define NROWS 8192   // B*S
#define DIN   1024
#define NT    12
#define NDEP  3
#define NDEC  36     // NT*NDEP
#define NCOL  48     // 36 decision + 12 gate logits
#define NC    96     // NT*NLEAF
#define NH    3
#define DOUT  512
#define LRP   52     // padded Lred row (f32)
#define CLP   104    // padded C_lds row (bf16)

typedef short bf16x8 __attribute__((ext_vector_type(8)));   // 8 bf16 = 4 VGPRs (MFMA A/B frag)
typedef float f32x4  __attribute__((ext_vector_type(4)));   // MFMA C/D frag

__device__ inline unsigned short f2bf(float f) {            // round-to-nearest-even
    unsigned u = __float_as_uint(f);
    u = u + 0x7fff + ((u >> 16) & 1);
    return (unsigned short)(u >> 16);
}
__device__ inline float bf2f(unsigned short h) {
    return __uint_as_float(((unsigned)h) << 16);
}
// packed RTNE f32x2 -> bf16x2 (low16 = a, high16 = b)
__device__ inline unsigned cvt_pk(float a, float b) {
    unsigned r;
    asm("v_cvt_pk_bf16_f32 %0, %1, %2" : "=v"(r) : "v"(a), "v"(b));
    return r;
}
// split 8 consecutive f32 into bf16 hi + bf16 lo fragments (exact residual)
__device__ inline void split8(const float4 a, const float4 b, bf16x8& hi, bf16x8& lo) {
    union U { unsigned u[4]; bf16x8 v; };
    U H, L;
    H.u[0] = cvt_pk(a.x, a.y); H.u[1] = cvt_pk(a.z, a.w);
    H.u[2] = cvt_pk(b.x, b.y); H.u[3] = cvt_pk(b.z, b.w);
    const float r0 = a.x - __uint_as_float(H.u[0] << 16);
    const float r1 = a.y - __uint_as_float(H.u[0] & 0xffff0000u);
    const float r2 = a.z - __uint_as_float(H.u[1] << 16);
    const float r3 = a.w - __uint_as_float(H.u[1] & 0xffff0000u);
    const float r4 = b.x - __uint_as_float(H.u[2] << 16);
    const float r5 = b.y - __uint_as_float(H.u[2] & 0xffff0000u);
    const float r6 = b.z - __uint_as_float(H.u[3] << 16);
    const float r7 = b.w - __uint_as_float(H.u[3] & 0xffff0000u);
    L.u[0] = cvt_pk(r0, r1); L.u[1] = cvt_pk(r2, r3);
    L.u[2] = cvt_pk(r4, r5); L.u[3] = cvt_pk(r6, r7);
    hi = H.v; lo = L.v;
}

// ---------------------------------------------------------------------------
// k_prep (merged): blocks [0,192): W[48][1024] -> bf16 hi/lo split ([n][k]);
// blocks [192,264): leafT[h][d][k] bf16; block 264: param tables.
// ---------------------------------------------------------------------------
__global__ __launch_bounds__(256) void k_prep(const float* __restrict__ dw,
                                              const float* __restrict__ gw,
                                              const float* __restrict__ db,
                                              const float* __restrict__ ntl,
                                              const float* __restrict__ leaf,
                                              unsigned short* __restrict__ w_hi,
                                              unsigned short* __restrict__ w_lo,
                                              unsigned short* __restrict__ leafT,
                                              float* __restrict__ it_zb) {
    const int b = blockIdx.x;
    if (b < 192) {
        const int i = b * 256 + threadIdx.x;        // n*1024 + k
        const int n = i >> 10;
        const float v = (n < NDEC) ? dw[i] : gw[i - NDEC * DIN];
        const unsigned short h = f2bf(v);
        w_hi[i] = h;
        w_lo[i] = f2bf(v - bf2f(h));
    } else if (b < 264) {
        const int i  = (b - 192) * 256 + threadIdx.x;   // 0 .. 18431
        const int hq = i % (NH * DOUT);                 // h*512 + d
        const int kq = i / (NH * DOUT);                 // 0..11
        const int h  = hq >> 9, d = hq & 511;
        bf16x8 v;
#pragma unroll
        for (int e = 0; e < 8; ++e)
            v[e] = (short)f2bf(leaf[(size_t)(h * NC + kq * 8 + e) * DOUT + d]);
        *(bf16x8*)(leafT + (size_t)hq * NC + kq * 8) = v;
    } else {
        const int i = threadIdx.x;
        if (i < NDEC) {
            const float v  = ntl[i] + 0.5413f;
            const float sp = (v > 20.0f) ? v : logf(1.0f + expf(v));
            const float it = 1.0f / sp;
            it_zb[i]        = it;            // inv_temp
            it_zb[NDEC + i] = db[i] * it;    // pre-scaled bias
        }
    }
}

// ---------------------------------------------------------------------------
// k_fused: block = 16 rows, 8 waves (512 thr), 512 blocks (16 waves/CU).
//   phase 1: GEMM1, wave w covers K-chunk [w*128,(w+1)*128); A=w, B=x so the
//            D-frag is 4 consecutive w-cols per lane -> f32x4 LDS write.
//            unroll 2 caps in-flight VGPRs (R5's full unroll regressed).
//   phase 2: LDS reduce (8 partials) + epilogue -> Cl bf16[16][96] in LDS.
//   phase 3: GEMM2, wave covers 12 of 96 col-frags; A=leafT, B=C so the
//            D-frag is 4 consecutive d per lane -> f32x4 coalesced store.
// ---------------------------------------------------------------------------
__global__ __launch_bounds__(512) void k_fused(const float* __restrict__ x,
                                               const unsigned short* __restrict__ w_hi,
                                               const unsigned short* __restrict__ w_lo,
                                               const unsigned short* __restrict__ leafT,
                                               const float* __restrict__ it_zb,
                                               const float* __restrict__ gb,
                                               float* __restrict__ out) {
    __shared__ __align__(16) float Lred[8][16][LRP];     // [wave][row][wcol]
    __shared__ __align__(16) unsigned short Cl[16][CLP];

    const int tid  = threadIdx.x;
    const int wv   = tid >> 6, lane = tid & 63;
    const int m    = lane & 15;                         // A: w-col / B: x-row
    const int kq   = lane >> 4;                         // k quarter (0..3)
    const int row0 = blockIdx.x * 16;

    // ---------------- phase 1: GEMM1 over this wave's K-chunk ----------------
    f32x4 acc[3];
#pragma unroll
    for (int nf = 0; nf < 3; ++nf)
#pragma unroll
        for (int r = 0; r < 4; ++r) acc[nf][r] = 0.0f;

    const float*          xp  = x    + (size_t)(row0 + m) * DIN + wv * 128 + kq * 8;
    const unsigned short* whp = w_hi + (size_t)m * DIN + wv * 128 + kq * 8;
    const unsigned short* wlp = w_lo + (size_t)m * DIN + wv * 128 + kq * 8;

#pragma unroll 2
    for (int ks = 0; ks < 4; ++ks) {
        const float4 xa = *(const float4*)(xp + ks * 32);
        const float4 xb = *(const float4*)(xp + ks * 32 + 4);
        bf16x8 xhi, xlo;
        split8(xa, xb, xhi, xlo);
#pragma unroll
        for (int nf = 0; nf < 3; ++nf) {
            const bf16x8 whi = *(const bf16x8*)(whp + (size_t)nf * 16 * DIN + ks * 32);
            const bf16x8 wlo = *(const bf16x8*)(wlp + (size_t)nf * 16 * DIN + ks * 32);
            acc[nf] = __builtin_amdgcn_mfma_f32_16x16x32_bf16(whi, xhi, acc[nf], 0, 0, 0);
            acc[nf] = __builtin_amdgcn_mfma_f32_16x16x32_bf16(whi, xlo, acc[nf], 0, 0, 0);
            acc[nf] = __builtin_amdgcn_mfma_f32_16x16x32_bf16(wlo, xhi, acc[nf], 0, 0, 0);
        }
    }
    // D: col(lane&15) = x-row, rows = 4 consecutive w-cols -> f32x4 LDS write
#pragma unroll
    for (int nf = 0; nf < 3; ++nf)
        *(f32x4*)&Lred[wv][m][nf * 16 + kq * 4] = acc[nf];
    __syncthreads();

    // ---------------- phase 2: reduce + epilogue (first 4 waves) ------------
    if (tid < 256) {
        const int erow = tid >> 4;      // 0..15  (row within block)
        const int slot = tid & 15;      // 0..11 = tree, 12..15 idle
        float lg0 = 0.f, lg1 = 0.f, lg2 = 0.f, g = -1e30f;
        if (slot < NT) {
            float lgg = 0.f;
#pragma unroll
            for (int w = 0; w < 8; ++w) {
                lg0 += Lred[w][erow][slot * 3 + 0];
                lg1 += Lred[w][erow][slot * 3 + 1];
                lg2 += Lred[w][erow][slot * 3 + 2];
                lgg += Lred[w][erow][NDEC + slot];
            }
            g = lgg + gb[slot];
        }
        // softmax over the 16-lane row-group (slots >= 12 contribute 0)
        float mx = g;
#pragma unroll
        for (int off = 1; off < 16; off <<= 1) mx = fmaxf(mx, __shfl_xor(mx, off, 16));
        const float e = (slot < NT) ? expf(g - mx) : 0.f;
        float s = e;
#pragma unroll
        for (int off = 1; off < 16; off <<= 1) s += __shfl_xor(s, off, 16);
        if (slot < NT) {
            const float wt = e * __builtin_amdgcn_rcpf(s);
            const float z0 = lg0 * it_zb[slot * 3 + 0] + it_zb[NDEC + slot * 3 + 0];
            const float z1 = lg1 * it_zb[slot * 3 + 1] + it_zb[NDEC + slot * 3 + 1];
            const float z2 = lg2 * it_zb[slot * 3 + 2] + it_zb[NDEC + slot * 3 + 2];
            const float d0 = __builtin_amdgcn_rcpf(1.0f + expf(-z0));
            const float d1 = __builtin_amdgcn_rcpf(1.0f + expf(-z1));
            const float d2 = __builtin_amdgcn_rcpf(1.0f + expf(-z2));
            float c[8];
#pragma unroll
            for (int l = 0; l < 8; ++l) {
                const float p0 = (l & 4) ? (1.0f - d0) : d0;
                const float p1 = (l & 2) ? (1.0f - d1) : d1;
                const float p2 = (l & 1) ? (1.0f - d2) : d2;
                c[l] = wt * p0 * p1 * p2;
            }
            union { unsigned u[4]; bf16x8 v; } P;
            P.u[0] = cvt_pk(c[0], c[1]); P.u[1] = cvt_pk(c[2], c[3]);
            P.u[2] = cvt_pk(c[4], c[5]); P.u[3] = cvt_pk(c[6], c[7]);
            *(bf16x8*)&Cl[erow][slot * 8] = P.v;
        }
    }
    __syncthreads();

    // ---------------- phase 3: GEMM2, wave covers 12 of 96 col-fragments ----
    bf16x8 cfr[3];
#pragma unroll
    for (int ks = 0; ks < 3; ++ks)
        cfr[ks] = *(const bf16x8*)&Cl[m][ks * 32 + kq * 8];

#pragma unroll
    for (int i = 0; i < 12; ++i) {
        const int f  = wv * 12 + i;           // 0..95
        const int h  = f >> 5;                // 512/16 = 32 frags per head
        const int d0 = (f & 31) * 16;
        const unsigned short* bp = leafT + ((size_t)h * DOUT + d0 + m) * NC + kq * 8;
        f32x4 a;
#pragma unroll
        for (int r = 0; r < 4; ++r) a[r] = 0.0f;
#pragma unroll
        for (int ks = 0; ks < 3; ++ks) {
            const bf16x8 lfr = *(const bf16x8*)(bp + ks * 32);
            a = __builtin_amdgcn_mfma_f32_16x16x32_bf16(lfr, cfr[ks], a, 0, 0, 0);
        }
        // D: col(lane&15) = out-row, regs = 4 consecutive d -> f32x4 store
        *(f32x4*)(out + ((size_t)h * NROWS + row0 + m) * DOUT + d0 + kq * 4) = a;
    }
}

extern "C" void kernel_launch(void* const* d_in, const int* in_sizes, int n_in,
                              void* d_out, int out_size, void* d_ws, size_t ws_size,
                              hipStream_t stream) {
    const float* x    = (const float*)d_in[0];
    const float* dw   = (const float*)d_in[1];
    const float* db   = (const float*)d_in[2];
    const float* ntl  = (const float*)d_in[3];
    const float* gw   = (const float*)d_in[4];
    const float* gb   = (const float*)d_in[5];
    const float* leaf = (const float*)d_in[6];
    float* out = (float*)d_out;

    // workspace carve (byte offsets, all 16B-aligned)
    char* ws = (char*)d_ws;
    unsigned short* w_hi  = (unsigned short*)(ws);            // 48*1024*2 =  98304 B
    unsigned short* w_lo  = (unsigned short*)(ws + 98304);    //              98304 B
    unsigned short* leafT = (unsigned short*)(ws + 196608);   // 3*512*96*2 = 294912 B
    float*          it_zb = (float*)(ws + 491520);            // 72*4       =    288 B

    k_prep<<<265, 256, 0, stream>>>(dw, gw, db, ntl, leaf, w_hi, w_lo, leafT, it_zb);
    k_fused<<<NROWS / 16, 512, 0, stream>>>(x, w_hi, w_lo, leafT, it_zb, gb, out);
}

// Round 11
// 39.258 us; speedup vs baseline: 1.1959x; 1.1087x over previous
//
#include <hip/hip_runtime.h>
#include <math.h>

// Problem dims (fixed by setup_inputs)
#define NROWS 8192   // B*S
#define DIN   1024
#define NT    12
#define NDEP  3
#define NDEC  36     // NT*NDEP
#define NCOL  48     // 36 decision + 12 gate logits
#define NC    96     // NT*NLEAF
#define NH    3
#define DOUT  512
#define CLP   104    // padded C_lds row (bf16): 96 -> 104 keeps 16B align, spreads banks

typedef short bf16x8 __attribute__((ext_vector_type(8)));   // 8 bf16 = 4 VGPRs (MFMA A/B frag)
typedef float f32x4  __attribute__((ext_vector_type(4)));   // MFMA C/D frag

__device__ inline unsigned short f2bf(float f) {            // round-to-nearest-even
    unsigned u = __float_as_uint(f);
    u = u + 0x7fff + ((u >> 16) & 1);
    return (unsigned short)(u >> 16);
}
__device__ inline float bf2f(unsigned short h) {
    return __uint_as_float(((unsigned)h) << 16);
}
// packed RTNE f32x2 -> bf16x2 (low16 = a, high16 = b)
__device__ inline unsigned cvt_pk(float a, float b) {
    unsigned r;
    asm("v_cvt_pk_bf16_f32 %0, %1, %2" : "=v"(r) : "v"(a), "v"(b));
    return r;
}
// split 8 consecutive f32 into bf16 hi + bf16 lo fragments (exact residual)
__device__ inline void split8(const float4 a, const float4 b, bf16x8& hi, bf16x8& lo) {
    union U { unsigned u[4]; bf16x8 v; };
    U H, L;
    H.u[0] = cvt_pk(a.x, a.y); H.u[1] = cvt_pk(a.z, a.w);
    H.u[2] = cvt_pk(b.x, b.y); H.u[3] = cvt_pk(b.z, b.w);
    const float r0 = a.x - __uint_as_float(H.u[0] << 16);
    const float r1 = a.y - __uint_as_float(H.u[0] & 0xffff0000u);
    const float r2 = a.z - __uint_as_float(H.u[1] << 16);
    const float r3 = a.w - __uint_as_float(H.u[1] & 0xffff0000u);
    const float r4 = b.x - __uint_as_float(H.u[2] << 16);
    const float r5 = b.y - __uint_as_float(H.u[2] & 0xffff0000u);
    const float r6 = b.z - __uint_as_float(H.u[3] << 16);
    const float r7 = b.w - __uint_as_float(H.u[3] & 0xffff0000u);
    L.u[0] = cvt_pk(r0, r1); L.u[1] = cvt_pk(r2, r3);
    L.u[2] = cvt_pk(r4, r5); L.u[3] = cvt_pk(r6, r7);
    hi = H.v; lo = L.v;
}

// ---------------------------------------------------------------------------
// k_prep (merged): blocks [0,192): W[48][1024] -> bf16 hi/lo split ([n][k]);
// blocks [192,264): leafT[h][d][k] bf16; block 264: param tables
// inv_temp[36] = 1/softplus(ntl+0.5413), zb[36] = db * inv_temp.
// ---------------------------------------------------------------------------
__global__ __launch_bounds__(256) void k_prep(const float* __restrict__ dw,
                                              const float* __restrict__ gw,
                                              const float* __restrict__ db,
                                              const float* __restrict__ ntl,
                                              const float* __restrict__ leaf,
                                              unsigned short* __restrict__ w_hi,
                                              unsigned short* __restrict__ w_lo,
                                              unsigned short* __restrict__ leafT,
                                              float* __restrict__ it_zb) {
    const int b = blockIdx.x;
    if (b < 192) {
        const int i = b * 256 + threadIdx.x;        // n*1024 + k
        const int n = i >> 10;
        const float v = (n < NDEC) ? dw[i] : gw[i - NDEC * DIN];
        const unsigned short h = f2bf(v);
        w_hi[i] = h;
        w_lo[i] = f2bf(v - bf2f(h));
    } else if (b < 264) {
        const int i  = (b - 192) * 256 + threadIdx.x;   // 0 .. 18431
        const int hq = i % (NH * DOUT);                 // h*512 + d
        const int kq = i / (NH * DOUT);                 // 0..11
        const int h  = hq >> 9, d = hq & 511;
        bf16x8 v;
#pragma unroll
        for (int e = 0; e < 8; ++e)
            v[e] = (short)f2bf(leaf[(size_t)(h * NC + kq * 8 + e) * DOUT + d]);
        *(bf16x8*)(leafT + (size_t)hq * NC + kq * 8) = v;
    } else {
        const int i = threadIdx.x;
        if (i < NDEC) {
            const float v  = ntl[i] + 0.5413f;
            const float sp = (v > 20.0f) ? v : logf(1.0f + expf(v));
            const float it = 1.0f / sp;
            it_zb[i]        = it;            // inv_temp
            it_zb[NDEC + i] = db[i] * it;    // pre-scaled bias
        }
    }
}

// ---------------------------------------------------------------------------
// k_fused: per block = 16 rows, 4 waves.  (EXACT text of the 39.1 µs pass.)
//   phase 1: GEMM1  (wave w covers K-chunk [w*256,(w+1)*256), split-bf16 MFMA)
//   phase 2: LDS reduce + epilogue (sigmoid/leaf/softmax) -> C_lds bf16[16][96]
//   phase 3: GEMM2  (wave w covers 24 of the 96 16-col output fragments)
// NOTE: the A=leafT/B=C swapped phase-3 at 4 waves x 24 frags fails
// validation (absmax 4.8e-2, R8-R10) despite per-element-identical semantics
// to the passing 8-wave/12-frag variant — codegen artifact.  Do not swap
// phase-3 operands in this 4-wave/24-frag shape.  nontemporal stores also
// unvalidated (R8).
// ---------------------------------------------------------------------------
__global__ __launch_bounds__(256) void k_fused(const float* __restrict__ x,
                                               const unsigned short* __restrict__ w_hi,
                                               const unsigned short* __restrict__ w_lo,
                                               const unsigned short* __restrict__ leafT,
                                               const float* __restrict__ it_zb,
                                               const float* __restrict__ gb,
                                               float* __restrict__ out) {
    __shared__ float Lred[4][NCOL][17];                 // padded: conflict-free writes
    __shared__ __align__(16) unsigned short Cl[16][CLP];

    const int tid  = threadIdx.x;
    const int wv   = tid >> 6, lane = tid & 63;
    const int m    = lane & 15;                         // MFMA m / n lane index
    const int kq   = lane >> 4;                         // k quarter (0..3)
    const int row0 = blockIdx.x * 16;

    // ---------------- phase 1: GEMM1 over this wave's K-chunk ----------------
    f32x4 acc[3];
#pragma unroll
    for (int nf = 0; nf < 3; ++nf)
#pragma unroll
        for (int r = 0; r < 4; ++r) acc[nf][r] = 0.0f;

    const float*          xp  = x    + (size_t)(row0 + m) * DIN + wv * 256 + kq * 8;
    const unsigned short* whp = w_hi + (size_t)m * DIN + wv * 256 + kq * 8;
    const unsigned short* wlp = w_lo + (size_t)m * DIN + wv * 256 + kq * 8;

#pragma unroll
    for (int ks = 0; ks < 8; ++ks) {
        const float4 xa = *(const float4*)(xp + ks * 32);
        const float4 xb = *(const float4*)(xp + ks * 32 + 4);
        bf16x8 xhi, xlo;
        split8(xa, xb, xhi, xlo);
#pragma unroll
        for (int nf = 0; nf < 3; ++nf) {
            const bf16x8 whi = *(const bf16x8*)(whp + (size_t)nf * 16 * DIN + ks * 32);
            const bf16x8 wlo = *(const bf16x8*)(wlp + (size_t)nf * 16 * DIN + ks * 32);
            acc[nf] = __builtin_amdgcn_mfma_f32_16x16x32_bf16(xhi, whi, acc[nf], 0, 0, 0);
            acc[nf] = __builtin_amdgcn_mfma_f32_16x16x32_bf16(xlo, whi, acc[nf], 0, 0, 0);
            acc[nf] = __builtin_amdgcn_mfma_f32_16x16x32_bf16(xhi, wlo, acc[nf], 0, 0, 0);
        }
    }
    // D layout: col(lane&15) = n, row = kq*4 + r
#pragma unroll
    for (int nf = 0; nf < 3; ++nf)
#pragma unroll
        for (int r = 0; r < 4; ++r)
            Lred[wv][nf * 16 + m][kq * 4 + r] = acc[nf][r];
    __syncthreads();

    // ---------------- phase 2: reduce + epilogue ----------------
    {
        const int erow = tid >> 4;      // 0..15  (row within block)
        const int slot = tid & 15;      // 0..11 = tree, 12..15 idle
        float lg0 = 0.f, lg1 = 0.f, lg2 = 0.f, g = -1e30f;
        if (slot < NT) {
            float lgg = 0.f;
#pragma unroll
            for (int w = 0; w < 4; ++w) {
                lg0 += Lred[w][slot * 3 + 0][erow];
                lg1 += Lred[w][slot * 3 + 1][erow];
                lg2 += Lred[w][slot * 3 + 2][erow];
                lgg += Lred[w][NDEC + slot][erow];
            }
            g = lgg + gb[slot];
        }
        // softmax over the 16-lane row-group (slots >= 12 contribute 0)
        float mx = g;
#pragma unroll
        for (int off = 1; off < 16; off <<= 1) mx = fmaxf(mx, __shfl_xor(mx, off, 16));
        const float e = (slot < NT) ? expf(g - mx) : 0.f;
        float s = e;
#pragma unroll
        for (int off = 1; off < 16; off <<= 1) s += __shfl_xor(s, off, 16);
        if (slot < NT) {
            const float wt = e * __builtin_amdgcn_rcpf(s);
            const float z0 = lg0 * it_zb[slot * 3 + 0] + it_zb[NDEC + slot * 3 + 0];
            const float z1 = lg1 * it_zb[slot * 3 + 1] + it_zb[NDEC + slot * 3 + 1];
            const float z2 = lg2 * it_zb[slot * 3 + 2] + it_zb[NDEC + slot * 3 + 2];
            const float d0 = __builtin_amdgcn_rcpf(1.0f + expf(-z0));
            const float d1 = __builtin_amdgcn_rcpf(1.0f + expf(-z1));
            const float d2 = __builtin_amdgcn_rcpf(1.0f + expf(-z2));
            float c[8];
#pragma unroll
            for (int l = 0; l < 8; ++l) {
                const float p0 = (l & 4) ? (1.0f - d0) : d0;
                const float p1 = (l & 2) ? (1.0f - d1) : d1;
                const float p2 = (l & 1) ? (1.0f - d2) : d2;
                c[l] = wt * p0 * p1 * p2;
            }
            union { unsigned u[4]; bf16x8 v; } P;
            P.u[0] = cvt_pk(c[0], c[1]); P.u[1] = cvt_pk(c[2], c[3]);
            P.u[2] = cvt_pk(c[4], c[5]); P.u[3] = cvt_pk(c[6], c[7]);
            *(bf16x8*)&Cl[erow][slot * 8] = P.v;
        }
    }
    __syncthreads();

    // ---------------- phase 3: GEMM2, wave covers 24 of 96 col-fragments ----
    bf16x8 afr[3];
#pragma unroll
    for (int ks = 0; ks < 3; ++ks)
        afr[ks] = *(const bf16x8*)&Cl[m][ks * 32 + kq * 8];

#pragma unroll
    for (int i = 0; i < 24; ++i) {
        const int f   = wv * 24 + i;          // 0..95
        const int h   = f >> 5;               // 512/16 = 32 frags per head
        const int d0c = (f & 31) * 16;
        const unsigned short* bp = leafT + ((size_t)h * DOUT + d0c + m) * NC + kq * 8;
        f32x4 a;
#pragma unroll
        for (int r = 0; r < 4; ++r) a[r] = 0.0f;
#pragma unroll
        for (int ks = 0; ks < 3; ++ks) {
            const bf16x8 bfr = *(const bf16x8*)(bp + ks * 32);
            a = __builtin_amdgcn_mfma_f32_16x16x32_bf16(afr[ks], bfr, a, 0, 0, 0);
        }
        float* op = out + ((size_t)h * NROWS + row0 + kq * 4) * DOUT + d0c + m;
#pragma unroll
        for (int r = 0; r < 4; ++r) op[(size_t)r * DOUT] = a[r];
    }
}

extern "C" void kernel_launch(void* const* d_in, const int* in_sizes, int n_in,
                              void* d_out, int out_size, void* d_ws, size_t ws_size,
                              hipStream_t stream) {
    const float* x    = (const float*)d_in[0];
    const float* dw   = (const float*)d_in[1];
    const float* db   = (const float*)d_in[2];
    const float* ntl  = (const float*)d_in[3];
    const float* gw   = (const float*)d_in[4];
    const float* gb   = (const float*)d_in[5];
    const float* leaf = (const float*)d_in[6];
    float* out = (float*)d_out;

    // workspace carve (byte offsets, all 16B-aligned)
    char* ws = (char*)d_ws;
    unsigned short* w_hi  = (unsigned short*)(ws);            // 48*1024*2 =  98304 B
    unsigned short* w_lo  = (unsigned short*)(ws + 98304);    //              98304 B
    unsigned short* leafT = (unsigned short*)(ws + 196608);   // 3*512*96*2 = 294912 B
    float*          it_zb = (float*)(ws + 491520);            // 72*4       =    288 B

    k_prep<<<265, 256, 0, stream>>>(dw, gw, db, ntl, leaf, w_hi, w_lo, leafT, it_zb);
    k_fused<<<NROWS / 16, 256, 0, stream>>>(x, w_hi, w_lo, leafT, it_zb, gb, out);
}